// Round 2
// baseline (522.137 us; speedup 1.0000x reference)
//
#include <hip/hip_runtime.h>
#include <hip/hip_bf16.h>

#define B_ 4
#define N_ 4096
#define C_ 64
#define R_ 16
#define EPS_ 1e-12f

typedef __attribute__((ext_vector_type(8))) short bf16x8;
typedef __attribute__((ext_vector_type(4))) float f32x4;

static __device__ __forceinline__ unsigned short f2bf(float f) {
    unsigned int u = __float_as_uint(f);
    unsigned int r = (u + 0x7fffu + ((u >> 16) & 1u)) >> 16;
    return (unsigned short)r;
}
static __device__ __forceinline__ float bf2f(unsigned short us) {
    return __uint_as_float(((unsigned int)us) << 16);
}

// Pass 1: tile pair (ti<=tj): K0 = 0.5*(W+W^T)*sigmoid(U U^T), write both
// orientations as bf16, accumulate deg row sums via quad-shfl + atomics.
// 2 barriers per batch; batch b+1 tiles prefetched into regs during phase A.
__global__ __launch_bounds__(256) void k_pass1(
    const float* __restrict__ W, const float* __restrict__ U,
    unsigned short* __restrict__ K0, float* __restrict__ deg)
{
    const int tj = blockIdx.x, ti = blockIdx.y;
    if (ti > tj) return;
    const int I = ti * 64, J = tj * 64;
    const bool diag = (ti == tj);
    const int t = threadIdx.x;
    const int ii = t >> 2, g = t & 3, jjg = g * 16;

    __shared__ float UJ[64][17];
    __shared__ float Wc[64][65];
    __shared__ __align__(16) unsigned short K0s[64][72]; // 144B rows, b128-writable

    // ---- prologue: stage UJ, issue b=0 tile loads, load ui ----
    {
        const float4 v = *(const float4*)(U + (size_t)(J + (t >> 2)) * R_ + (t & 3) * 4);
        UJ[t >> 2][(t & 3) * 4 + 0] = v.x;
        UJ[t >> 2][(t & 3) * 4 + 1] = v.y;
        UJ[t >> 2][(t & 3) * 4 + 2] = v.z;
        UJ[t >> 2][(t & 3) * 4 + 3] = v.w;
    }

    float4 wcv[4], wrv[4], wcvN[4], wrvN[4];
    #pragma unroll
    for (int k = 0; k < 4; k++) {
        const int idx = t + 256 * k, row = idx >> 4, c4 = idx & 15;
        wcv[k] = *(const float4*)(W + ((size_t)(0 * N_ + J + row)) * N_ + I + c4 * 4);
    }
    #pragma unroll
    for (int h = 0; h < 4; h++)
        wrv[h] = *(const float4*)(W + ((size_t)(0 * N_ + I + ii)) * N_ + J + jjg + 4 * h);

    float ui[16];
    {
        const float* up = U + (size_t)(I + ii) * R_;
        #pragma unroll
        for (int h = 0; h < 4; h++) {
            float4 v = *(const float4*)(up + 4 * h);
            ui[4*h] = v.x; ui[4*h+1] = v.y; ui[4*h+2] = v.z; ui[4*h+3] = v.w;
        }
    }
    __syncthreads(); // UJ ready

    float a[16];
    #pragma unroll
    for (int q = 0; q < 16; q++) {
        float s = 0.f;
        #pragma unroll
        for (int k = 0; k < 16; k++) s += ui[k] * UJ[jjg + q][k];
        a[q] = 1.0f / (1.0f + __expf(-s));
    }

    // write Wc for b=0 (no barrier needed vs UJ reads: different buffers)
    #pragma unroll
    for (int k = 0; k < 4; k++) {
        const int idx = t + 256 * k, row = idx >> 4, c4 = idx & 15;
        Wc[row][c4*4+0] = wcv[k].x; Wc[row][c4*4+1] = wcv[k].y;
        Wc[row][c4*4+2] = wcv[k].z; Wc[row][c4*4+3] = wcv[k].w;
    }
    __syncthreads(); // Wc ready for b=0

    for (int b = 0; b < B_; b++) {
        // ---- phase A: prefetch b+1, compute k0, write K0s + row-orient global ----
        if (b < B_ - 1) {
            #pragma unroll
            for (int k = 0; k < 4; k++) {
                const int idx = t + 256 * k, row = idx >> 4, c4 = idx & 15;
                wcvN[k] = *(const float4*)(W + ((size_t)((b+1) * N_ + J + row)) * N_ + I + c4 * 4);
            }
            #pragma unroll
            for (int h = 0; h < 4; h++)
                wrvN[h] = *(const float4*)(W + ((size_t)((b+1) * N_ + I + ii)) * N_ + J + jjg + 4 * h);
        }

        const float* wrf = (const float*)wrv;
        float sumI = 0.f;
        unsigned int pk[8];
        #pragma unroll
        for (int q = 0; q < 16; q++) {
            float k0 = 0.5f * (wrf[q] + Wc[jjg + q][ii]) * a[q];
            sumI += k0;
            unsigned short us = f2bf(k0);
            if (q & 1) pk[q >> 1] |= ((unsigned int)us) << 16;
            else       pk[q >> 1] = us;
        }
        *(int4*)(&K0s[ii][jjg])     = make_int4(pk[0], pk[1], pk[2], pk[3]);
        *(int4*)(&K0s[ii][jjg + 8]) = make_int4(pk[4], pk[5], pk[6], pk[7]);
        {
            unsigned short* dst = K0 + ((size_t)(b * N_ + I + ii)) * N_ + J + jjg;
            *(int4*)(dst)     = make_int4(pk[0], pk[1], pk[2], pk[3]);
            *(int4*)(dst + 8) = make_int4(pk[4], pk[5], pk[6], pk[7]);
        }
        // row-sum: quad reduce (lanes ii*4+g are consecutive) then 1 atomic/row
        {
            float s = sumI + __shfl_xor(sumI, 1, 64);
            s += __shfl_xor(s, 2, 64);
            if (g == 0) atomicAdd(deg + b * N_ + I + ii, s);
        }
        __syncthreads(); // K0s ready; Wc reads done

        // ---- phase B: transposed global write + col sums; stage next Wc ----
        if (!diag) {
            const int c2 = t & 31, r8 = t >> 5; // thread: rows r8*8..+7, cols 2c2,2c2+1
            unsigned int v[8];
            float cs0 = 0.f, cs1 = 0.f;
            #pragma unroll
            for (int k = 0; k < 8; k++) {
                v[k] = *(const unsigned int*)(&K0s[r8 * 8 + k][c2 * 2]);
                cs0 += bf2f((unsigned short)(v[k] & 0xffffu));
                cs1 += bf2f((unsigned short)(v[k] >> 16));
            }
            unsigned int plo[4], phi[4];
            #pragma unroll
            for (int m = 0; m < 4; m++) {
                plo[m] = (v[2*m] & 0xffffu) | (v[2*m+1] << 16);
                phi[m] = (v[2*m] >> 16) | (v[2*m+1] & 0xffff0000u);
            }
            unsigned short* dst0 = K0 + ((size_t)(b * N_ + J + 2 * c2)) * N_ + I + r8 * 8;
            unsigned short* dst1 = dst0 + N_;
            *(int4*)dst0 = make_int4(plo[0], plo[1], plo[2], plo[3]);
            *(int4*)dst1 = make_int4(phi[0], phi[1], phi[2], phi[3]);
            // col sums: reduce over r8 pairs within wave (xor 32), then atomics
            cs0 += __shfl_xor(cs0, 32, 64);
            cs1 += __shfl_xor(cs1, 32, 64);
            if ((t & 32) == 0) {
                atomicAdd(deg + b * N_ + J + 2 * c2,     cs0);
                atomicAdd(deg + b * N_ + J + 2 * c2 + 1, cs1);
            }
        }
        if (b < B_ - 1) {
            #pragma unroll
            for (int k = 0; k < 4; k++) {
                const int idx = t + 256 * k, row = idx >> 4, c4 = idx & 15;
                Wc[row][c4*4+0] = wcvN[k].x; Wc[row][c4*4+1] = wcvN[k].y;
                Wc[row][c4*4+2] = wcvN[k].z; Wc[row][c4*4+3] = wcvN[k].w;
            }
            #pragma unroll
            for (int h = 0; h < 4; h++) wrv[h] = wrvN[h];
            __syncthreads(); // Wc ready; K0s reads done
        }
    }
}

// xdT[b, c, j] = bf16( x[b, j, c] * rsqrt(max(deg[b,j],EPS)) )
__global__ __launch_bounds__(256) void k_xdT(
    const float* __restrict__ x, const float* __restrict__ deg,
    unsigned short* __restrict__ xdT)
{
    const int jt = blockIdx.x, b = blockIdx.y;
    const int J = jt * 64, t = threadIdx.x;
    __shared__ float xt[64][69]; // 69: (5r+c) bank map, conflict-free col reads
    #pragma unroll
    for (int k = 0; k < 4; k++) {
        int idx = t + 256 * k;
        int row = idx >> 4, f4 = idx & 15;
        float d = rsqrtf(fmaxf(deg[b * N_ + J + row], EPS_));
        float4 v = *(const float4*)(x + ((size_t)(b * N_ + J + row)) * C_ + f4 * 4);
        xt[row][f4*4+0] = v.x * d; xt[row][f4*4+1] = v.y * d;
        xt[row][f4*4+2] = v.z * d; xt[row][f4*4+3] = v.w * d;
    }
    __syncthreads();
    const int c = t >> 2, jg = (t & 3) * 16;
    unsigned int pk[8];
    #pragma unroll
    for (int q = 0; q < 16; q++) {
        unsigned short us = f2bf(xt[jg + q][c]);
        if (q & 1) pk[q >> 1] |= ((unsigned int)us) << 16;
        else       pk[q >> 1] = us;
    }
    unsigned short* dst = xdT + ((size_t)(b * C_ + c)) * N_ + J + jg;
    *(int4*)(dst)     = make_int4(pk[0], pk[1], pk[2], pk[3]);
    *(int4*)(dst + 8) = make_int4(pk[4], pk[5], pk[6], pk[7]);
}

// Pass 2: LDS-free MFMA GEMM. Block = 16 out rows; wave w covers cols w*16..+15.
// Fragments loaded straight from global (A rows of K0, B rows of xdT).
__global__ __launch_bounds__(256) void k_gemm(
    const unsigned short* __restrict__ K0, const unsigned short* __restrict__ xdT,
    const float* __restrict__ deg, const float* __restrict__ wsc_p,
    float* __restrict__ out)
{
    const int rb = blockIdx.x, b = blockIdx.y;
    const int I = rb * 16;
    const int t = threadIdx.x, l = t & 63, w = t >> 6;
    const int fr = l & 15, fq = l >> 4, cw = w * 16;

    const unsigned short* Ap = K0  + ((size_t)(b * N_ + I + fr)) * N_ + fq * 8;
    const unsigned short* Bp = xdT + ((size_t)(b * C_ + cw + fr)) * N_ + fq * 8;

    f32x4 acc0 = {0.f, 0.f, 0.f, 0.f}, acc1 = {0.f, 0.f, 0.f, 0.f};
    #pragma unroll 8
    for (int k = 0; k < N_; k += 64) {
        bf16x8 a0 = *(const bf16x8*)(Ap + k);
        bf16x8 b0 = *(const bf16x8*)(Bp + k);
        bf16x8 a1 = *(const bf16x8*)(Ap + k + 32);
        bf16x8 b1 = *(const bf16x8*)(Bp + k + 32);
        acc0 = __builtin_amdgcn_mfma_f32_16x16x32_bf16(a0, b0, acc0, 0, 0, 0);
        acc1 = __builtin_amdgcn_mfma_f32_16x16x32_bf16(a1, b1, acc1, 0, 0, 0);
    }
    f32x4 acc = acc0 + acc1;

    const float wsc = wsc_p[0];
    #pragma unroll
    for (int r = 0; r < 4; r++) {
        const int row = I + fq * 4 + r;
        const float sc = wsc * rsqrtf(fmaxf(deg[b * N_ + row], EPS_));
        out[((size_t)(b * N_ + row)) * C_ + cw + fr] = sc * acc[r];
    }
}

extern "C" void kernel_launch(void* const* d_in, const int* in_sizes, int n_in,
                              void* d_out, int out_size, void* d_ws, size_t ws_size,
                              hipStream_t stream)
{
    const float* x   = (const float*)d_in[0];
    const float* W   = (const float*)d_in[1];
    const float* U   = (const float*)d_in[2];
    const float* wsc = (const float*)d_in[3];
    float* out = (float*)d_out;

    // workspace: K0 (bf16, 128 MiB) | deg (fp32, 64 KiB) | xdT (bf16, 2 MiB)
    unsigned short* K0  = (unsigned short*)d_ws;
    float*          deg = (float*)((char*)d_ws + (size_t)B_ * N_ * N_ * 2);
    unsigned short* xdT = (unsigned short*)((char*)deg + (size_t)B_ * N_ * 4);

    hipMemsetAsync(deg, 0, (size_t)B_ * N_ * sizeof(float), stream);
    hipLaunchKernelGGL(k_pass1, dim3(64, 64), dim3(256), 0, stream, W, U, K0, deg);
    hipLaunchKernelGGL(k_xdT,  dim3(64, 4),   dim3(256), 0, stream, x, deg, xdT);
    hipLaunchKernelGGL(k_gemm, dim3(256, 4),  dim3(256), 0, stream, K0, xdT, deg, wsc, out);
}

// Round 3
// 463.458 us; speedup vs baseline: 1.1266x; 1.1266x over previous
//
#include <hip/hip_runtime.h>
#include <hip/hip_bf16.h>

#define B_ 4
#define N_ 4096
#define C_ 64
#define R_ 16
#define EPS_ 1e-12f

typedef __attribute__((ext_vector_type(8))) short bf16x8;
typedef __attribute__((ext_vector_type(4))) float f32x4;

static __device__ __forceinline__ unsigned short f2bf(float f) {
    unsigned int u = __float_as_uint(f);
    unsigned int r = (u + 0x7fffu + ((u >> 16) & 1u)) >> 16;
    return (unsigned short)r;
}
static __device__ __forceinline__ float bf2f(unsigned short us) {
    return __uint_as_float(((unsigned int)us) << 16);
}

// K0f fragment layout: [b][rowtile=row/16][k32=k/32][fq=(k/8)&3][fr=row&15][e=k&7]
// One wave's A fragment for (rowtile,k32) = contiguous 1 KiB, lane l at +l*16B.
static __device__ __forceinline__ size_t k0f_off(int b, int rt, int k32, int fq, int fr) {
    return ((((size_t)(b * 256 + rt)) * 128 + k32) * 4 + fq) * 128 + fr * 8;
}

// Pass 1: tile pair (ti<=tj): K0 = 0.5*(W+W^T)*sigmoid(U U^T), write both
// orientations in MFMA-fragment layout, deg row sums via shfl + atomics.
__global__ __launch_bounds__(256) void k_pass1(
    const float* __restrict__ W, const float* __restrict__ U,
    unsigned short* __restrict__ K0, float* __restrict__ deg)
{
    const int tj = blockIdx.x, ti = blockIdx.y;
    if (ti > tj) return;
    const int I = ti * 64, J = tj * 64;
    const bool diag = (ti == tj);
    const int t = threadIdx.x;
    const int ii = t >> 2, g = t & 3, jjg = g * 16;

    __shared__ float UJ[64][17];
    __shared__ float Wc[64][65];
    __shared__ __align__(16) unsigned short K0s[64][72];

    {
        const float4 v = *(const float4*)(U + (size_t)(J + (t >> 2)) * R_ + (t & 3) * 4);
        UJ[t >> 2][(t & 3) * 4 + 0] = v.x;
        UJ[t >> 2][(t & 3) * 4 + 1] = v.y;
        UJ[t >> 2][(t & 3) * 4 + 2] = v.z;
        UJ[t >> 2][(t & 3) * 4 + 3] = v.w;
    }

    float4 wcv[4], wrv[4], wcvN[4], wrvN[4];
    #pragma unroll
    for (int k = 0; k < 4; k++) {
        const int idx = t + 256 * k, row = idx >> 4, c4 = idx & 15;
        wcv[k] = *(const float4*)(W + ((size_t)(0 * N_ + J + row)) * N_ + I + c4 * 4);
    }
    #pragma unroll
    for (int h = 0; h < 4; h++)
        wrv[h] = *(const float4*)(W + ((size_t)(0 * N_ + I + ii)) * N_ + J + jjg + 4 * h);

    float ui[16];
    {
        const float* up = U + (size_t)(I + ii) * R_;
        #pragma unroll
        for (int h = 0; h < 4; h++) {
            float4 v = *(const float4*)(up + 4 * h);
            ui[4*h] = v.x; ui[4*h+1] = v.y; ui[4*h+2] = v.z; ui[4*h+3] = v.w;
        }
    }
    __syncthreads(); // UJ ready

    float a[16];
    #pragma unroll
    for (int q = 0; q < 16; q++) {
        float s = 0.f;
        #pragma unroll
        for (int k = 0; k < 16; k++) s += ui[k] * UJ[jjg + q][k];
        a[q] = 1.0f / (1.0f + __expf(-s));
    }

    #pragma unroll
    for (int k = 0; k < 4; k++) {
        const int idx = t + 256 * k, row = idx >> 4, c4 = idx & 15;
        Wc[row][c4*4+0] = wcv[k].x; Wc[row][c4*4+1] = wcv[k].y;
        Wc[row][c4*4+2] = wcv[k].z; Wc[row][c4*4+3] = wcv[k].w;
    }
    __syncthreads(); // Wc ready for b=0

    for (int b = 0; b < B_; b++) {
        if (b < B_ - 1) {
            #pragma unroll
            for (int k = 0; k < 4; k++) {
                const int idx = t + 256 * k, row = idx >> 4, c4 = idx & 15;
                wcvN[k] = *(const float4*)(W + ((size_t)((b+1) * N_ + J + row)) * N_ + I + c4 * 4);
            }
            #pragma unroll
            for (int h = 0; h < 4; h++)
                wrvN[h] = *(const float4*)(W + ((size_t)((b+1) * N_ + I + ii)) * N_ + J + jjg + 4 * h);
        }

        const float* wrf = (const float*)wrv;
        float sumI = 0.f;
        unsigned int pk[8];
        #pragma unroll
        for (int q = 0; q < 16; q++) {
            float k0 = 0.5f * (wrf[q] + Wc[jjg + q][ii]) * a[q];
            sumI += k0;
            unsigned short us = f2bf(k0);
            if (q & 1) pk[q >> 1] |= ((unsigned int)us) << 16;
            else       pk[q >> 1] = us;
        }
        *(int4*)(&K0s[ii][jjg])     = make_int4(pk[0], pk[1], pk[2], pk[3]);
        *(int4*)(&K0s[ii][jjg + 8]) = make_int4(pk[4], pk[5], pk[6], pk[7]);
        // row-orientation fragment store: row I+ii, k = J+g*16 .. +15
        {
            const int rt  = (I + ii) >> 4, fr = ii & 15;
            const int k32 = (J >> 5) + (g >> 1), fqa = (g & 1) * 2;
            unsigned short* dst = K0 + k0f_off(b, rt, k32, fqa, fr);
            *(int4*)(dst)       = make_int4(pk[0], pk[1], pk[2], pk[3]);
            *(int4*)(dst + 128) = make_int4(pk[4], pk[5], pk[6], pk[7]);
        }
        {
            float s = sumI + __shfl_xor(sumI, 1, 64);
            s += __shfl_xor(s, 2, 64);
            if (g == 0) atomicAdd(deg + b * N_ + I + ii, s);
        }
        __syncthreads(); // K0s ready; Wc reads done

        if (!diag) {
            const int c2 = t & 31, r8 = t >> 5; // cols j=2c2,2c2+1; rows i=r8*8..+7
            unsigned int v[8];
            float cs0 = 0.f, cs1 = 0.f;
            #pragma unroll
            for (int k = 0; k < 8; k++) {
                v[k] = *(const unsigned int*)(&K0s[r8 * 8 + k][c2 * 2]);
                cs0 += bf2f((unsigned short)(v[k] & 0xffffu));
                cs1 += bf2f((unsigned short)(v[k] >> 16));
            }
            unsigned int plo[4], phi[4];
            #pragma unroll
            for (int m = 0; m < 4; m++) {
                plo[m] = (v[2*m] & 0xffffu) | (v[2*m+1] << 16);
                phi[m] = (v[2*m] >> 16) | (v[2*m+1] & 0xffff0000u);
            }
            // transposed fragment store: out row J+2c2(+1), k = I+r8*8 .. +7
            const int rtp  = (J >> 4) + (c2 >> 3), fr0 = (2 * c2) & 15;
            const int k32p = (I >> 5) + (r8 >> 2), fqp = r8 & 3;
            unsigned short* dst0 = K0 + k0f_off(b, rtp, k32p, fqp, fr0);
            *(int4*)(dst0)     = make_int4(plo[0], plo[1], plo[2], plo[3]);
            *(int4*)(dst0 + 8) = make_int4(phi[0], phi[1], phi[2], phi[3]);
            cs0 += __shfl_xor(cs0, 32, 64);
            cs1 += __shfl_xor(cs1, 32, 64);
            if ((t & 32) == 0) {
                atomicAdd(deg + b * N_ + J + 2 * c2,     cs0);
                atomicAdd(deg + b * N_ + J + 2 * c2 + 1, cs1);
            }
        }
        if (b < B_ - 1) {
            #pragma unroll
            for (int k = 0; k < 4; k++) {
                const int idx = t + 256 * k, row = idx >> 4, c4 = idx & 15;
                Wc[row][c4*4+0] = wcvN[k].x; Wc[row][c4*4+1] = wcvN[k].y;
                Wc[row][c4*4+2] = wcvN[k].z; Wc[row][c4*4+3] = wcvN[k].w;
            }
            #pragma unroll
            for (int h = 0; h < 4; h++) wrv[h] = wrvN[h];
            __syncthreads(); // Wc ready; K0s reads done
        }
    }
}

// xdTf fragment layout: [b][k32=j/32][cg=c/16][fq=(j/8)&3][fr=c&15][e=j&7]
// value = bf16( x[b,j,c] * rsqrt(deg[b,j]) )
__global__ __launch_bounds__(256) void k_xdT(
    const float* __restrict__ x, const float* __restrict__ deg,
    unsigned short* __restrict__ xdT)
{
    const int jt = blockIdx.x, b = blockIdx.y;
    const int J = jt * 64, t = threadIdx.x;
    __shared__ float xt[64][69];
    #pragma unroll
    for (int k = 0; k < 4; k++) {
        int idx = t + 256 * k;
        int row = idx >> 4, f4 = idx & 15;
        float d = rsqrtf(fmaxf(deg[b * N_ + J + row], EPS_));
        float4 v = *(const float4*)(x + ((size_t)(b * N_ + J + row)) * C_ + f4 * 4);
        xt[row][f4*4+0] = v.x * d; xt[row][f4*4+1] = v.y * d;
        xt[row][f4*4+2] = v.z * d; xt[row][f4*4+3] = v.w * d;
    }
    __syncthreads();
    #pragma unroll
    for (int p = 0; p < 2; p++) {
        const int linear = p * 256 + t;
        const int k32h = linear >> 8, rem = linear & 255;
        const int cg = rem >> 6, l = rem & 63, fq = l >> 4, fr = l & 15;
        const int c = cg * 16 + fr;
        const int jb = k32h * 32 + fq * 8;
        unsigned int pk[4];
        #pragma unroll
        for (int m = 0; m < 4; m++) {
            pk[m] = (unsigned int)f2bf(xt[jb + 2*m][c]) |
                    ((unsigned int)f2bf(xt[jb + 2*m + 1][c]) << 16);
        }
        unsigned short* dst = xdT +
            (((size_t)(b * 128 + (J >> 5) + k32h)) * 4 + cg) * 512 + l * 8;
        *(int4*)dst = make_int4(pk[0], pk[1], pk[2], pk[3]);
    }
}

// Pass 2: barrier-free MFMA GEMM on pre-swizzled fragments.
// Block = 64 out rows; wave w owns rowtile rb*4+w (16 rows) x all 64 cols.
// A: unique per wave, 1 KiB coalesced loads, read once chip-wide (HBM-bound).
// B: 512 KiB/batch, L2-resident, 4x re-read from L2 (cheap).
__global__ __launch_bounds__(256) void k_gemm(
    const unsigned short* __restrict__ K0, const unsigned short* __restrict__ xdT,
    const float* __restrict__ deg, const float* __restrict__ wsc_p,
    float* __restrict__ out)
{
    const int rb = blockIdx.x, b = blockIdx.y;
    const int t = threadIdx.x, l = t & 63, w = t >> 6;
    const int rt = rb * 4 + w;

    const unsigned short* Ap = K0  + (size_t)(b * 256 + rt) * 65536 + l * 8;
    const unsigned short* Bp = xdT + (size_t)b * 262144 + l * 8;

    f32x4 acc0 = {0.f,0.f,0.f,0.f}, acc1 = {0.f,0.f,0.f,0.f};
    f32x4 acc2 = {0.f,0.f,0.f,0.f}, acc3 = {0.f,0.f,0.f,0.f};

    #pragma unroll 4
    for (int k32 = 0; k32 < 128; k32++) {
        bf16x8 av = *(const bf16x8*)(Ap + (size_t)k32 * 512);
        bf16x8 b0 = *(const bf16x8*)(Bp + (size_t)k32 * 2048);
        bf16x8 b1 = *(const bf16x8*)(Bp + (size_t)k32 * 2048 + 512);
        bf16x8 b2 = *(const bf16x8*)(Bp + (size_t)k32 * 2048 + 1024);
        bf16x8 b3 = *(const bf16x8*)(Bp + (size_t)k32 * 2048 + 1536);
        acc0 = __builtin_amdgcn_mfma_f32_16x16x32_bf16(av, b0, acc0, 0, 0, 0);
        acc1 = __builtin_amdgcn_mfma_f32_16x16x32_bf16(av, b1, acc1, 0, 0, 0);
        acc2 = __builtin_amdgcn_mfma_f32_16x16x32_bf16(av, b2, acc2, 0, 0, 0);
        acc3 = __builtin_amdgcn_mfma_f32_16x16x32_bf16(av, b3, acc3, 0, 0, 0);
    }

    const int fr = l & 15, fq = l >> 4;
    const float wsc = wsc_p[0];
    #pragma unroll
    for (int r = 0; r < 4; r++) {
        const int row = rt * 16 + fq * 4 + r;
        const float sc = wsc * rsqrtf(fmaxf(deg[b * N_ + row], EPS_));
        float* op = out + ((size_t)(b * N_ + row)) * C_;
        op[fr]      = sc * acc0[r];
        op[16 + fr] = sc * acc1[r];
        op[32 + fr] = sc * acc2[r];
        op[48 + fr] = sc * acc3[r];
    }
}

extern "C" void kernel_launch(void* const* d_in, const int* in_sizes, int n_in,
                              void* d_out, int out_size, void* d_ws, size_t ws_size,
                              hipStream_t stream)
{
    const float* x   = (const float*)d_in[0];
    const float* W   = (const float*)d_in[1];
    const float* U   = (const float*)d_in[2];
    const float* wsc = (const float*)d_in[3];
    float* out = (float*)d_out;

    // workspace: K0f (bf16, 128 MiB) | deg (fp32, 64 KiB) | xdTf (bf16, 2 MiB)
    unsigned short* K0  = (unsigned short*)d_ws;
    float*          deg = (float*)((char*)d_ws + (size_t)B_ * N_ * N_ * 2);
    unsigned short* xdT = (unsigned short*)((char*)deg + (size_t)B_ * N_ * 4);

    hipMemsetAsync(deg, 0, (size_t)B_ * N_ * sizeof(float), stream);
    hipLaunchKernelGGL(k_pass1, dim3(64, 64), dim3(256), 0, stream, W, U, K0, deg);
    hipLaunchKernelGGL(k_xdT,  dim3(64, 4),  dim3(256), 0, stream, x, deg, xdT);
    hipLaunchKernelGGL(k_gemm, dim3(64, 4),  dim3(256), 0, stream, K0, xdT, deg, wsc, out);
}

// Round 4
// 458.336 us; speedup vs baseline: 1.1392x; 1.0112x over previous
//
#include <hip/hip_runtime.h>
#include <hip/hip_bf16.h>

#define B_ 4
#define N_ 4096
#define C_ 64
#define R_ 16
#define EPS_ 1e-12f

typedef __attribute__((ext_vector_type(8))) short bf16x8;
typedef __attribute__((ext_vector_type(4))) float f32x4;

static __device__ __forceinline__ unsigned short f2bf(float f) {
    unsigned int u = __float_as_uint(f);
    unsigned int r = (u + 0x7fffu + ((u >> 16) & 1u)) >> 16;
    return (unsigned short)r;
}
static __device__ __forceinline__ float bf2f(unsigned short us) {
    return __uint_as_float(((unsigned int)us) << 16);
}

// K0f fragment layout: [b][rowtile=row/16][k32=k/32][fq=(k/8)&3][fr=row&15][e=k&7]
// One wave's A fragment for (rowtile,k32) = contiguous 1 KiB, lane l at +l*16B.
static __device__ __forceinline__ size_t k0f_off(int b, int rt, int k32, int fq, int fr) {
    return ((((size_t)(b * 256 + rt)) * 128 + k32) * 4 + fq) * 128 + fr * 8;
}

// Pass 1: tile pair (ti<=tj): K0 = 0.5*(W+W^T)*sigmoid(U U^T), write both
// orientations in MFMA-fragment layout, deg row sums via shfl + atomics.
__global__ __launch_bounds__(256) void k_pass1(
    const float* __restrict__ W, const float* __restrict__ U,
    unsigned short* __restrict__ K0, float* __restrict__ deg)
{
    const int tj = blockIdx.x, ti = blockIdx.y;
    if (ti > tj) return;
    const int I = ti * 64, J = tj * 64;
    const bool diag = (ti == tj);
    const int t = threadIdx.x;
    const int ii = t >> 2, g = t & 3, jjg = g * 16;

    __shared__ float UJ[64][17];
    __shared__ float Wc[64][65];
    __shared__ __align__(16) unsigned short K0s[64][72];

    {
        const float4 v = *(const float4*)(U + (size_t)(J + (t >> 2)) * R_ + (t & 3) * 4);
        UJ[t >> 2][(t & 3) * 4 + 0] = v.x;
        UJ[t >> 2][(t & 3) * 4 + 1] = v.y;
        UJ[t >> 2][(t & 3) * 4 + 2] = v.z;
        UJ[t >> 2][(t & 3) * 4 + 3] = v.w;
    }

    float4 wcv[4], wrv[4], wcvN[4], wrvN[4];
    #pragma unroll
    for (int k = 0; k < 4; k++) {
        const int idx = t + 256 * k, row = idx >> 4, c4 = idx & 15;
        wcv[k] = *(const float4*)(W + ((size_t)(0 * N_ + J + row)) * N_ + I + c4 * 4);
    }
    #pragma unroll
    for (int h = 0; h < 4; h++)
        wrv[h] = *(const float4*)(W + ((size_t)(0 * N_ + I + ii)) * N_ + J + jjg + 4 * h);

    float ui[16];
    {
        const float* up = U + (size_t)(I + ii) * R_;
        #pragma unroll
        for (int h = 0; h < 4; h++) {
            float4 v = *(const float4*)(up + 4 * h);
            ui[4*h] = v.x; ui[4*h+1] = v.y; ui[4*h+2] = v.z; ui[4*h+3] = v.w;
        }
    }
    __syncthreads(); // UJ ready

    float a[16];
    #pragma unroll
    for (int q = 0; q < 16; q++) {
        float s = 0.f;
        #pragma unroll
        for (int k = 0; k < 16; k++) s += ui[k] * UJ[jjg + q][k];
        a[q] = 1.0f / (1.0f + __expf(-s));
    }

    #pragma unroll
    for (int k = 0; k < 4; k++) {
        const int idx = t + 256 * k, row = idx >> 4, c4 = idx & 15;
        Wc[row][c4*4+0] = wcv[k].x; Wc[row][c4*4+1] = wcv[k].y;
        Wc[row][c4*4+2] = wcv[k].z; Wc[row][c4*4+3] = wcv[k].w;
    }
    __syncthreads(); // Wc ready for b=0

    for (int b = 0; b < B_; b++) {
        if (b < B_ - 1) {
            #pragma unroll
            for (int k = 0; k < 4; k++) {
                const int idx = t + 256 * k, row = idx >> 4, c4 = idx & 15;
                wcvN[k] = *(const float4*)(W + ((size_t)((b+1) * N_ + J + row)) * N_ + I + c4 * 4);
            }
            #pragma unroll
            for (int h = 0; h < 4; h++)
                wrvN[h] = *(const float4*)(W + ((size_t)((b+1) * N_ + I + ii)) * N_ + J + jjg + 4 * h);
        }

        const float* wrf = (const float*)wrv;
        float sumI = 0.f;
        unsigned int pk[8];
        #pragma unroll
        for (int q = 0; q < 16; q++) {
            float k0 = 0.5f * (wrf[q] + Wc[jjg + q][ii]) * a[q];
            sumI += k0;
            unsigned short us = f2bf(k0);
            if (q & 1) pk[q >> 1] |= ((unsigned int)us) << 16;
            else       pk[q >> 1] = us;
        }
        *(int4*)(&K0s[ii][jjg])     = make_int4(pk[0], pk[1], pk[2], pk[3]);
        *(int4*)(&K0s[ii][jjg + 8]) = make_int4(pk[4], pk[5], pk[6], pk[7]);
        // row-orientation fragment store: row I+ii, k = J+g*16 .. +15
        {
            const int rt  = (I + ii) >> 4, fr = ii & 15;
            const int k32 = (J >> 5) + (g >> 1), fqa = (g & 1) * 2;
            unsigned short* dst = K0 + k0f_off(b, rt, k32, fqa, fr);
            *(int4*)(dst)       = make_int4(pk[0], pk[1], pk[2], pk[3]);
            *(int4*)(dst + 128) = make_int4(pk[4], pk[5], pk[6], pk[7]);
        }
        {
            float s = sumI + __shfl_xor(sumI, 1, 64);
            s += __shfl_xor(s, 2, 64);
            if (g == 0) atomicAdd(deg + b * N_ + I + ii, s);
        }
        __syncthreads(); // K0s ready; Wc reads done

        if (!diag) {
            const int c2 = t & 31, r8 = t >> 5; // cols j=2c2,2c2+1; rows i=r8*8..+7
            unsigned int v[8];
            float cs0 = 0.f, cs1 = 0.f;
            #pragma unroll
            for (int k = 0; k < 8; k++) {
                v[k] = *(const unsigned int*)(&K0s[r8 * 8 + k][c2 * 2]);
                cs0 += bf2f((unsigned short)(v[k] & 0xffffu));
                cs1 += bf2f((unsigned short)(v[k] >> 16));
            }
            unsigned int plo[4], phi[4];
            #pragma unroll
            for (int m = 0; m < 4; m++) {
                plo[m] = (v[2*m] & 0xffffu) | (v[2*m+1] << 16);
                phi[m] = (v[2*m] >> 16) | (v[2*m+1] & 0xffff0000u);
            }
            // transposed fragment store: out row J+2c2(+1), k = I+r8*8 .. +7
            const int rtp  = (J >> 4) + (c2 >> 3), fr0 = (2 * c2) & 15;
            const int k32p = (I >> 5) + (r8 >> 2), fqp = r8 & 3;
            unsigned short* dst0 = K0 + k0f_off(b, rtp, k32p, fqp, fr0);
            *(int4*)(dst0)     = make_int4(plo[0], plo[1], plo[2], plo[3]);
            *(int4*)(dst0 + 8) = make_int4(phi[0], phi[1], phi[2], phi[3]);
            cs0 += __shfl_xor(cs0, 32, 64);
            cs1 += __shfl_xor(cs1, 32, 64);
            if ((t & 32) == 0) {
                atomicAdd(deg + b * N_ + J + 2 * c2,     cs0);
                atomicAdd(deg + b * N_ + J + 2 * c2 + 1, cs1);
            }
        }
        if (b < B_ - 1) {
            #pragma unroll
            for (int k = 0; k < 4; k++) {
                const int idx = t + 256 * k, row = idx >> 4, c4 = idx & 15;
                Wc[row][c4*4+0] = wcvN[k].x; Wc[row][c4*4+1] = wcvN[k].y;
                Wc[row][c4*4+2] = wcvN[k].z; Wc[row][c4*4+3] = wcvN[k].w;
            }
            #pragma unroll
            for (int h = 0; h < 4; h++) wrv[h] = wrvN[h];
            __syncthreads(); // Wc ready; K0s reads done
        }
    }
}

// xdTf fragment layout: [b][k32=j/32][cg=c/16][fq=(j/8)&3][fr=c&15][e=j&7]
// value = bf16( x[b,j,c] * rsqrt(deg[b,j]) )
__global__ __launch_bounds__(256) void k_xdT(
    const float* __restrict__ x, const float* __restrict__ deg,
    unsigned short* __restrict__ xdT)
{
    const int jt = blockIdx.x, b = blockIdx.y;
    const int J = jt * 64, t = threadIdx.x;
    __shared__ float xt[64][69];
    #pragma unroll
    for (int k = 0; k < 4; k++) {
        int idx = t + 256 * k;
        int row = idx >> 4, f4 = idx & 15;
        float d = rsqrtf(fmaxf(deg[b * N_ + J + row], EPS_));
        float4 v = *(const float4*)(x + ((size_t)(b * N_ + J + row)) * C_ + f4 * 4);
        xt[row][f4*4+0] = v.x * d; xt[row][f4*4+1] = v.y * d;
        xt[row][f4*4+2] = v.z * d; xt[row][f4*4+3] = v.w * d;
    }
    __syncthreads();
    #pragma unroll
    for (int p = 0; p < 2; p++) {
        const int linear = p * 256 + t;
        const int k32h = linear >> 8, rem = linear & 255;
        const int cg = rem >> 6, l = rem & 63, fq = l >> 4, fr = l & 15;
        const int c = cg * 16 + fr;
        const int jb = k32h * 32 + fq * 8;
        unsigned int pk[4];
        #pragma unroll
        for (int m = 0; m < 4; m++) {
            pk[m] = (unsigned int)f2bf(xt[jb + 2*m][c]) |
                    ((unsigned int)f2bf(xt[jb + 2*m + 1][c]) << 16);
        }
        unsigned short* dst = xdT +
            (((size_t)(b * 128 + (J >> 5) + k32h)) * 4 + cg) * 512 + l * 8;
        *(int4*)dst = make_int4(pk[0], pk[1], pk[2], pk[3]);
    }
}

// Pass 2: split-K MFMA GEMM, 1 wave per (rowtile, K-quarter), no LDS/barriers.
// Grid (1024, 4) single-wave blocks -> ~16 waves/CU for HBM latency hiding.
// Pre-scaled fp32 atomicAdd into zeroed out (4 adds/element).
__global__ __launch_bounds__(64, 4) void k_gemm(
    const unsigned short* __restrict__ K0, const unsigned short* __restrict__ xdT,
    const float* __restrict__ deg, const float* __restrict__ wsc_p,
    float* __restrict__ out)
{
    const int blk = blockIdx.x, b = blockIdx.y;
    const int rt = blk >> 2, kq = blk & 3;   // rowtile 0..255, K-quarter 0..3
    const int l = threadIdx.x;

    const unsigned short* Ap = K0  + (size_t)(b * 256 + rt) * 65536
                                   + (size_t)(kq * 32) * 512 + l * 8;
    const unsigned short* Bp = xdT + (size_t)b * 262144
                                   + (size_t)(kq * 32) * 2048 + l * 8;

    f32x4 acc0 = {0.f,0.f,0.f,0.f}, acc1 = {0.f,0.f,0.f,0.f};
    f32x4 acc2 = {0.f,0.f,0.f,0.f}, acc3 = {0.f,0.f,0.f,0.f};

    #pragma unroll 4
    for (int k = 0; k < 32; k++) {
        bf16x8 av = *(const bf16x8*)(Ap + (size_t)k * 512);
        bf16x8 b0 = *(const bf16x8*)(Bp + (size_t)k * 2048);
        bf16x8 b1 = *(const bf16x8*)(Bp + (size_t)k * 2048 + 512);
        bf16x8 b2 = *(const bf16x8*)(Bp + (size_t)k * 2048 + 1024);
        bf16x8 b3 = *(const bf16x8*)(Bp + (size_t)k * 2048 + 1536);
        acc0 = __builtin_amdgcn_mfma_f32_16x16x32_bf16(av, b0, acc0, 0, 0, 0);
        acc1 = __builtin_amdgcn_mfma_f32_16x16x32_bf16(av, b1, acc1, 0, 0, 0);
        acc2 = __builtin_amdgcn_mfma_f32_16x16x32_bf16(av, b2, acc2, 0, 0, 0);
        acc3 = __builtin_amdgcn_mfma_f32_16x16x32_bf16(av, b3, acc3, 0, 0, 0);
    }

    const int fr = l & 15, fq = l >> 4;
    const float wsc = wsc_p[0];
    #pragma unroll
    for (int r = 0; r < 4; r++) {
        const int row = rt * 16 + fq * 4 + r;
        const float sc = wsc * rsqrtf(fmaxf(deg[b * N_ + row], EPS_));
        float* op = out + ((size_t)(b * N_ + row)) * C_;
        atomicAdd(op + fr,      sc * acc0[r]);
        atomicAdd(op + 16 + fr, sc * acc1[r]);
        atomicAdd(op + 32 + fr, sc * acc2[r]);
        atomicAdd(op + 48 + fr, sc * acc3[r]);
    }
}

extern "C" void kernel_launch(void* const* d_in, const int* in_sizes, int n_in,
                              void* d_out, int out_size, void* d_ws, size_t ws_size,
                              hipStream_t stream)
{
    const float* x   = (const float*)d_in[0];
    const float* W   = (const float*)d_in[1];
    const float* U   = (const float*)d_in[2];
    const float* wsc = (const float*)d_in[3];
    float* out = (float*)d_out;

    // workspace: K0f (bf16, 128 MiB) | deg (fp32, 64 KiB) | xdTf (bf16, 2 MiB)
    unsigned short* K0  = (unsigned short*)d_ws;
    float*          deg = (float*)((char*)d_ws + (size_t)B_ * N_ * N_ * 2);
    unsigned short* xdT = (unsigned short*)((char*)deg + (size_t)B_ * N_ * 4);

    hipMemsetAsync(deg, 0, (size_t)B_ * N_ * sizeof(float), stream);
    hipMemsetAsync(out, 0, (size_t)B_ * N_ * C_ * sizeof(float), stream);
    hipLaunchKernelGGL(k_pass1, dim3(64, 64), dim3(256), 0, stream, W, U, K0, deg);
    hipLaunchKernelGGL(k_xdT,  dim3(64, 4),   dim3(256), 0, stream, x, deg, xdT);
    hipLaunchKernelGGL(k_gemm, dim3(1024, 4), dim3(64),  0, stream, K0, xdT, deg, wsc, out);
}